// Round 3
// baseline (639.019 us; speedup 1.0000x reference)
//
#include <hip/hip_runtime.h>
#include <hip/hip_bf16.h>

#define T_TOK 1024
#define HDIM  2048
#define NEXP  8
#define IDIM  1408
#define SIDIM 5632
#define MAXSLOTS 24

typedef __attribute__((ext_vector_type(8))) short bf16x8;
typedef __attribute__((ext_vector_type(4))) float f32x4;
typedef unsigned short ushort_t;

__device__ __forceinline__ unsigned f2bf(float x) {
    unsigned u = __float_as_uint(x);
    return (u + 0x7fffu + ((u >> 16) & 1u)) >> 16;
}
__device__ __forceinline__ unsigned pack2(float a, float b) {
    return f2bf(a) | (f2bf(b) << 16);
}
__device__ __forceinline__ void async16(const void* g, void* l) {
    __builtin_amdgcn_global_load_lds(
        (const __attribute__((address_space(1))) void*)g,
        (__attribute__((address_space(3))) void*)l, 16, 0, 0);
}

// ---------------- Convert X: fp32 -> bf16 flat ----------------
__global__ __launch_bounds__(256) void conv_x(
    const float* __restrict__ src, ushort_t* __restrict__ dst)
{
    const int i = blockIdx.x * 256 + threadIdx.x;
    const float4* s = (const float4*)src + (size_t)i * 2;
    float4 a = s[0], b = s[1];
    union { ushort_t us[8]; uint4 v; } o;
    o.us[0] = (ushort_t)f2bf(a.x); o.us[1] = (ushort_t)f2bf(a.y);
    o.us[2] = (ushort_t)f2bf(a.z); o.us[3] = (ushort_t)f2bf(a.w);
    o.us[4] = (ushort_t)f2bf(b.x); o.us[5] = (ushort_t)f2bf(b.y);
    o.us[6] = (ushort_t)f2bf(b.z); o.us[7] = (ushort_t)f2bf(b.w);
    ((uint4*)dst)[i] = o.v;
}

// ------- Convert+transpose all weights: [K][N] f32 -> [N][K] bf16, one launch -------
// v3 layout (measured 0 bank conflicts): LDS [pair_row 32][68 words], XOR swizzle
//   word (P,col) at ldsw[P*68 + 4*((col>>2)^(P>>2)) + (col&3)].
__global__ __launch_bounds__(256) void conv_all(
    const float* __restrict__ wg, const float* __restrict__ wu,
    const float* __restrict__ wd, const float* __restrict__ swg,
    const float* __restrict__ swu, const float* __restrict__ swd,
    ushort_t* __restrict__ wtg, ushort_t* __restrict__ wtu,
    ushort_t* __restrict__ wtd, ushort_t* __restrict__ swtg,
    ushort_t* __restrict__ swtu, ushort_t* __restrict__ swtd)
{
    int id = blockIdx.x;
    const float* src; ushort_t* dst; int K, N, ktile, ntile;
    if (id < 11264) {
        const float* s0; ushort_t* d0;
        if (id < 5632) { s0 = wg; d0 = wtg; } else { s0 = wu; d0 = wtu; id -= 5632; }
        const int e = id / 704, t = id % 704;
        K = 2048; N = 1408;
        src = s0 + (size_t)e * K * N; dst = d0 + (size_t)e * K * N;
        ntile = t % 22; ktile = t / 22;
    } else if (id < 16896) {
        const int t2 = id - 11264;
        const int e = t2 / 704, t = t2 % 704;
        K = 1408; N = 2048;
        src = wd + (size_t)e * K * N; dst = wtd + (size_t)e * K * N;
        ntile = t % 32; ktile = t / 32;
    } else if (id < 22528) {
        int t2 = id - 16896; const float* s0; ushort_t* d0;
        if (t2 < 2816) { s0 = swg; d0 = swtg; } else { s0 = swu; d0 = swtu; t2 -= 2816; }
        K = 2048; N = 5632;
        src = s0; dst = d0;
        ntile = t2 % 88; ktile = t2 / 88;
    } else {
        const int t2 = id - 22528;
        K = 5632; N = 2048; src = swd; dst = swtd;
        ntile = t2 % 32; ktile = t2 / 32;
    }
    const int tid = threadIdx.x;
    __shared__ __align__(16) unsigned ldsw[32 * 68];
    const float* sp = src + (size_t)(ktile * 64) * N + ntile * 64;
    const int m = tid & 15;          // column group (16 groups x 4 cols)
    const int ph = tid >> 4;         // 0..15
#pragma unroll
    for (int h = 0; h < 2; ++h) {
        const int P = ph + h * 16;   // pair-row index 0..31
        const float* r0 = sp + (size_t)(2 * P) * N + m * 4;
        f32x4 a = __builtin_nontemporal_load((const f32x4*)r0);
        f32x4 b = __builtin_nontemporal_load((const f32x4*)(r0 + N));
        uint4 u;
        u.x = pack2(a[0], b[0]); u.y = pack2(a[1], b[1]);
        u.z = pack2(a[2], b[2]); u.w = pack2(a[3], b[3]);
        *(uint4*)&ldsw[P * 68 + 4 * (m ^ (P >> 2))] = u;
    }
    __syncthreads();
    ushort_t* dp = dst + (size_t)(ntile * 64) * K + ktile * 64;
#pragma unroll
    for (int j = 0; j < 2; ++j) {
        const int c = tid + j * 256;
        const int row = c >> 3, kc = c & 7;
        const int base = 4 * ((row >> 2) ^ kc) + (row & 3);
        uint4 v;
        v.x = ldsw[(4 * kc + 0) * 68 + base];
        v.y = ldsw[(4 * kc + 1) * 68 + base];
        v.z = ldsw[(4 * kc + 2) * 68 + base];
        v.w = ldsw[(4 * kc + 3) * 68 + base];
        *(uint4*)(dp + (size_t)row * K + kc * 8) = v;
    }
}

// ---------------- Router ----------------
__global__ __launch_bounds__(256) void router_kernel(
    const float* __restrict__ hs, const float* __restrict__ gw,
    const float* __restrict__ sgw, float* __restrict__ out_logits,
    float* __restrict__ w_dense, float* __restrict__ sgate,
    int* __restrict__ counts, int* __restrict__ tok_list)
{
    const int t = blockIdx.x;
    const int tid = threadIdx.x;
    const float* h = hs + (size_t)t * HDIM;
    float acc[9];
#pragma unroll
    for (int e = 0; e < 9; ++e) acc[e] = 0.f;
    for (int i = tid; i < HDIM; i += 256) {
        float hv = h[i];
        const float4* g4 = (const float4*)(gw + (size_t)i * NEXP);
        float4 g0 = g4[0], g1 = g4[1];
        acc[0] += hv * g0.x; acc[1] += hv * g0.y;
        acc[2] += hv * g0.z; acc[3] += hv * g0.w;
        acc[4] += hv * g1.x; acc[5] += hv * g1.y;
        acc[6] += hv * g1.z; acc[7] += hv * g1.w;
        acc[8] += hv * sgw[i];
    }
#pragma unroll
    for (int e = 0; e < 9; ++e)
        for (int off = 32; off > 0; off >>= 1)
            acc[e] += __shfl_down(acc[e], off, 64);
    __shared__ float lds[4][9];
    const int wid = tid >> 6, lane = tid & 63;
    if (lane == 0)
        for (int e = 0; e < 9; ++e) lds[wid][e] = acc[e];
    __syncthreads();
    if (tid == 0) {
        float l[9];
        for (int e = 0; e < 9; ++e)
            l[e] = lds[0][e] + lds[1][e] + lds[2][e] + lds[3][e];
        for (int e = 0; e < NEXP; ++e) out_logits[(size_t)t * NEXP + e] = l[e];
        float m = l[0];
        for (int e = 1; e < NEXP; ++e) m = fmaxf(m, l[e]);
        float p[NEXP], s = 0.f;
        for (int e = 0; e < NEXP; ++e) { p[e] = expf(l[e] - m); s += p[e]; }
        float inv = 1.f / s;
        for (int e = 0; e < NEXP; ++e) p[e] *= inv;
        int e0 = 0;
        for (int e = 1; e < NEXP; ++e) if (p[e] > p[e0]) e0 = e;
        int e1 = (e0 == 0) ? 1 : 0;
        for (int e = 0; e < NEXP; ++e) if (e != e0 && p[e] > p[e1]) e1 = e;
        for (int e = 0; e < NEXP; ++e)
            w_dense[(size_t)t * NEXP + e] = (e == e0) ? p[e0] : ((e == e1) ? p[e1] : 0.f);
        sgate[t] = 1.f / (1.f + expf(-l[8]));
        int p0 = atomicAdd(&counts[e0], 1); tok_list[e0 * T_TOK + p0] = t;
        int p1 = atomicAdd(&counts[e1], 1); tok_list[e1 * T_TOK + p1] = t;
    }
}

__global__ __launch_bounds__(64) void slot_kernel(
    const int* __restrict__ counts, int* __restrict__ slot_e,
    int* __restrict__ slot_rb, int* __restrict__ nslots)
{
    if (threadIdx.x == 0 && blockIdx.x == 0) {
        int ns = 0;
        for (int e = 0; e < NEXP; ++e)
            for (int b = 0; b < counts[e]; b += 128) {
                slot_e[ns] = e; slot_rb[ns] = b; ++ns;
            }
        nslots[0] = ns;
    }
}

// ---- Gate+Up merged (shared + routed): block 128M x 64N(x2 mats), BK=64 ----
// v4: 2-phase double-buffered pipeline — STAGE(t+1) issued before COMPUTE(t),
// one __syncthreads per K-step. LDS 64KB -> 2 blocks/CU; latency hidden in-block.
__global__ __launch_bounds__(256) void gateup_all(
    const ushort_t* __restrict__ Xb,
    const ushort_t* __restrict__ swtg, const ushort_t* __restrict__ swtu,
    const ushort_t* __restrict__ wtg, const ushort_t* __restrict__ wtu,
    ushort_t* __restrict__ Ysh, ushort_t* __restrict__ Yr,
    const int* __restrict__ slot_e, const int* __restrict__ slot_rb,
    const int* __restrict__ counts, const int* __restrict__ nslots,
    const int* __restrict__ tok_list, const ushort_t* __restrict__ zerobuf)
{
    const int id = blockIdx.x;
    int n0, slot, e, rowbase, N, mode;
    if (id < 704) {
        mode = 1; n0 = (id % 88) * 64; slot = id / 88; e = 0; rowbase = 0; N = SIDIM;
    } else {
        mode = 0;
        const int id2 = id - 704;
        n0 = (id2 % 22) * 64; slot = id2 / 22;
        if (slot >= nslots[0]) return;
        e = slot_e[slot]; rowbase = slot_rb[slot]; N = IDIM;
    }
    const ushort_t* __restrict__ Wg = mode ? swtg : wtg + (size_t)e * HDIM * IDIM;
    const ushort_t* __restrict__ Wu = mode ? swtu : wtu + (size_t)e * HDIM * IDIM;
    ushort_t* __restrict__ Y = mode ? Ysh : Yr;
    const int K = HDIM;

    const int tid = threadIdx.x, lane = tid & 63, wid = tid >> 6;
    const int wr = (wid >> 1) * 64;
    const int wc = (wid & 1) * 32;
    const int fm = lane & 15, kg = lane >> 4;

    __shared__ int ltok[128];
    __shared__ __align__(16) ushort_t Xa[2][128 * 64];
    __shared__ __align__(16) ushort_t Bgs[2][64 * 64];
    __shared__ __align__(16) ushort_t Bus[2][64 * 64];

    if (tid < 128) {
        int tg;
        if (mode == 0) {
            int cnt = counts[e];
            tg = (rowbase + tid < cnt) ? tok_list[e * T_TOK + rowbase + tid] : -1;
        } else {
            tg = slot * 128 + tid;
        }
        ltok[tid] = tg;
    }
    __syncthreads();

    f32x4 ag[4][2], au[4][2];
#pragma unroll
    for (int a = 0; a < 4; ++a)
#pragma unroll
        for (int b = 0; b < 2; ++b) {
            ag[a][b] = f32x4{0.f, 0.f, 0.f, 0.f};
            au[a][b] = f32x4{0.f, 0.f, 0.f, 0.f};
        }

    // per-thread swizzled k-offset (same for every issue)
    const int koff = (((tid & 7) ^ ((tid >> 3) & 7))) * 8;
    const ushort_t* pA[4];
#pragma unroll
    for (int j = 0; j < 4; ++j) {
        const int r = (tid >> 3) + j * 32;
        const int tk = ltok[r];
        pA[j] = (tk >= 0) ? Xb + (size_t)tk * K + koff : zerobuf;
    }
    const ushort_t* pG[2];
    const ushort_t* pU[2];
#pragma unroll
    for (int j = 0; j < 2; ++j) {
        const int r = (tid >> 3) + j * 32;
        pG[j] = Wg + (size_t)(n0 + r) * K + koff;
        pU[j] = Wu + (size_t)(n0 + r) * K + koff;
    }

#define STAGE_GU(buf, k0)                                                   \
    {                                                                       \
        _Pragma("unroll")                                                   \
        for (int j = 0; j < 4; ++j)                                         \
            async16(pA[j] + (k0), &Xa[buf][(j * 256 + wid * 64) * 8]);      \
        _Pragma("unroll")                                                   \
        for (int j = 0; j < 2; ++j) {                                       \
            async16(pG[j] + (k0), &Bgs[buf][(j * 256 + wid * 64) * 8]);     \
            async16(pU[j] + (k0), &Bus[buf][(j * 256 + wid * 64) * 8]);     \
        }                                                                   \
    }

    const int NT = K / 64;  // 32
    STAGE_GU(0, 0);
    __syncthreads();

    for (int t = 0; t < NT; ++t) {
        const int cur = t & 1;
        if (t + 1 < NT) STAGE_GU(cur ^ 1, (t + 1) * 64);

#pragma unroll
        for (int ks = 0; ks < 2; ++ks) {
            const int kx = ((ks * 4 + kg) ^ (fm & 7)) * 8;
            bf16x8 af[4];
#pragma unroll
            for (int mt = 0; mt < 4; ++mt)
                af[mt] = *(const bf16x8*)&Xa[cur][(wr + mt * 16 + fm) * 64 + kx];
#pragma unroll
            for (int nt = 0; nt < 2; ++nt) {
                const int rb = (wc + nt * 16 + fm) * 64 + kx;
                bf16x8 bg = *(const bf16x8*)&Bgs[cur][rb];
                bf16x8 bu = *(const bf16x8*)&Bus[cur][rb];
#pragma unroll
                for (int mt = 0; mt < 4; ++mt) {
                    ag[mt][nt] = __builtin_amdgcn_mfma_f32_16x16x32_bf16(af[mt], bg, ag[mt][nt], 0, 0, 0);
                    au[mt][nt] = __builtin_amdgcn_mfma_f32_16x16x32_bf16(af[mt], bu, au[mt][nt], 0, 0, 0);
                }
            }
        }
        __syncthreads();
    }
#undef STAGE_GU

#pragma unroll
    for (int mt = 0; mt < 4; ++mt)
#pragma unroll
        for (int nt = 0; nt < 2; ++nt) {
            const int col = n0 + wc + nt * 16 + fm;
#pragma unroll
            for (int i = 0; i < 4; ++i) {
                const int row = wr + mt * 16 + kg * 4 + i;
                float g = ag[mt][nt][i], u = au[mt][nt][i];
                float yv = g / (1.f + expf(-g)) * u;
                Y[(size_t)(slot * 128 + row) * N + col] = (ushort_t)f2bf(yv);
            }
        }
}

// ---- Down merged (shared z-split 4 + routed z-split 2): 128M x 128N, BK=64 ----
// v4: 2-phase double-buffered pipeline, one barrier per K-step.
__global__ __launch_bounds__(256) void down_all(
    const ushort_t* __restrict__ Ysh, const ushort_t* __restrict__ Yr,
    const ushort_t* __restrict__ swtd, const ushort_t* __restrict__ wtd,
    float* __restrict__ out,
    const int* __restrict__ slot_e, const int* __restrict__ slot_rb,
    const int* __restrict__ counts, const int* __restrict__ nslots,
    const int* __restrict__ tok_list, const float* __restrict__ w_dense,
    const float* __restrict__ sgate)
{
    const int id = blockIdx.x;
    int n0, slot, e, rowbase, K, kbase, ksteps, mode;
    const ushort_t* Yb;
    const ushort_t* Wd;
    if (id < 512) {
        mode = 1;
        n0 = (id & 15) * 128; slot = (id >> 4) & 7;
        const int z = id >> 7;
        K = SIDIM; kbase = z * 1408; ksteps = 22;
        e = 0; rowbase = 0;
        Yb = Ysh + (size_t)slot * 128 * K;
        Wd = swtd;
    } else {
        mode = 0;
        const int id2 = id - 512;
        n0 = (id2 & 15) * 128;
        const int rest = id2 >> 4;
        slot = rest >> 1;
        if (slot >= nslots[0]) return;
        const int z = rest & 1;
        K = IDIM; kbase = z * 704; ksteps = 11;
        e = slot_e[slot]; rowbase = slot_rb[slot];
        Yb = Yr + (size_t)slot * 128 * K;
        Wd = wtd + (size_t)e * IDIM * HDIM;
    }
    const int tid = threadIdx.x, lane = tid & 63, wid = tid >> 6;
    const int wr = (wid >> 1) * 64;
    const int wc = (wid & 1) * 64;
    const int fm = lane & 15, kg = lane >> 4;

    __shared__ int ltok[128];
    __shared__ float lw[128];
    __shared__ __align__(16) ushort_t Ya[2][128 * 64];
    __shared__ __align__(16) ushort_t Bd[2][128 * 64];

    if (tid < 128) {
        int tg; float wv;
        if (mode == 0) {
            int cnt = counts[e];
            if (rowbase + tid < cnt) {
                tg = tok_list[e * T_TOK + rowbase + tid];
                wv = w_dense[(size_t)tg * NEXP + e];
            } else { tg = -1; wv = 0.f; }
        } else {
            tg = slot * 128 + tid; wv = sgate[tg];
        }
        ltok[tid] = tg; lw[tid] = wv;
    }
    __syncthreads();

    f32x4 acc[4][4];
#pragma unroll
    for (int a = 0; a < 4; ++a)
#pragma unroll
        for (int b = 0; b < 4; ++b) acc[a][b] = f32x4{0.f, 0.f, 0.f, 0.f};

    const int koff = (((tid & 7) ^ ((tid >> 3) & 7))) * 8;
    const ushort_t* pY[4];
    const ushort_t* pW[4];
#pragma unroll
    for (int j = 0; j < 4; ++j) {
        const int r = (tid >> 3) + j * 32;
        pY[j] = Yb + (size_t)r * K + kbase + koff;
        pW[j] = Wd + (size_t)(n0 + r) * K + kbase + koff;
    }

#define STAGE_D(buf, k0)                                                    \
    {                                                                       \
        _Pragma("unroll")                                                   \
        for (int j = 0; j < 4; ++j) {                                       \
            async16(pY[j] + (k0), &Ya[buf][(j * 256 + wid * 64) * 8]);      \
            async16(pW[j] + (k0), &Bd[buf][(j * 256 + wid * 64) * 8]);      \
        }                                                                   \
    }

    STAGE_D(0, 0);
    __syncthreads();

    for (int s = 0; s < ksteps; ++s) {
        const int cur = s & 1;
        if (s + 1 < ksteps) STAGE_D(cur ^ 1, (s + 1) * 64);

#pragma unroll
        for (int ks = 0; ks < 2; ++ks) {
            const int kx = ((ks * 4 + kg) ^ (fm & 7)) * 8;
            bf16x8 af[4];
#pragma unroll
            for (int mt = 0; mt < 4; ++mt)
                af[mt] = *(const bf16x8*)&Ya[cur][(wr + mt * 16 + fm) * 64 + kx];
#pragma unroll
            for (int nt = 0; nt < 4; ++nt) {
                bf16x8 bf = *(const bf16x8*)&Bd[cur][(wc + nt * 16 + fm) * 64 + kx];
#pragma unroll
                for (int mt = 0; mt < 4; ++mt)
                    acc[mt][nt] = __builtin_amdgcn_mfma_f32_16x16x32_bf16(af[mt], bf, acc[mt][nt], 0, 0, 0);
            }
        }
        __syncthreads();
    }
#undef STAGE_D

#pragma unroll
    for (int mt = 0; mt < 4; ++mt)
#pragma unroll
        for (int nt = 0; nt < 4; ++nt) {
            const int col = n0 + wc + nt * 16 + fm;
#pragma unroll
            for (int i = 0; i < 4; ++i) {
                const int row = wr + mt * 16 + kg * 4 + i;
                const int tg = ltok[row];
                if (tg >= 0)
                    atomicAdd(out + (size_t)tg * HDIM + col, lw[row] * acc[mt][nt][i]);
            }
        }
}

extern "C" void kernel_launch(void* const* d_in, const int* in_sizes, int n_in,
                              void* d_out, int out_size, void* d_ws, size_t ws_size,
                              hipStream_t stream)
{
    const float* hs  = (const float*)d_in[0];
    const float* gw  = (const float*)d_in[1];
    const float* wg  = (const float*)d_in[2];
    const float* wu  = (const float*)d_in[3];
    const float* wd  = (const float*)d_in[4];
    const float* swg = (const float*)d_in[5];
    const float* swu = (const float*)d_in[6];
    const float* swd = (const float*)d_in[7];
    const float* sgw = (const float*)d_in[8];
    float* out = (float*)d_out;
    char* ws = (char*)d_ws;

    float* w_dense      = (float*)(ws + 0x00000);
    float* sgate        = (float*)(ws + 0x08000);
    int* counts         = (int*)(ws + 0x09000);
    int* nslots         = (int*)(ws + 0x09100);
    int* slot_e         = (int*)(ws + 0x09200);
    int* slot_rb        = (int*)(ws + 0x09300);
    int* tok_list       = (int*)(ws + 0x09400);
    ushort_t* zerobuf   = (ushort_t*)(ws + 0x11400);   // 16 KB zeros
    ushort_t* Xb        = (ushort_t*)(ws + 0x20000);
    ushort_t* Yr        = (ushort_t*)(ws + 0x420000);
    ushort_t* Ysh       = (ushort_t*)(ws + 0xC60000);
    ushort_t* wtg       = (ushort_t*)(ws + 0x1760000);
    ushort_t* wtu       = (ushort_t*)(ws + 0x4360000);
    ushort_t* wtd       = (ushort_t*)(ws + 0x6F60000);
    ushort_t* swtg      = (ushort_t*)(ws + 0x9B60000);
    ushort_t* swtu      = (ushort_t*)(ws + 0xB160000);
    ushort_t* swtd      = (ushort_t*)(ws + 0xC760000);
    float* out_logits = out + (size_t)T_TOK * HDIM;

    hipMemsetAsync(counts, 0, 256, stream);
    hipMemsetAsync(zerobuf, 0, 16384, stream);
    hipMemsetAsync(out, 0, (size_t)T_TOK * HDIM * sizeof(float), stream);

    conv_x<<<dim3(1024), dim3(256), 0, stream>>>(hs, Xb);
    conv_all<<<dim3(25344), dim3(256), 0, stream>>>(
        wg, wu, wd, swg, swu, swd, wtg, wtu, wtd, swtg, swtu, swtd);

    router_kernel<<<dim3(T_TOK), dim3(256), 0, stream>>>(
        hs, gw, sgw, out_logits, w_dense, sgate, counts, tok_list);
    slot_kernel<<<dim3(1), dim3(64), 0, stream>>>(counts, slot_e, slot_rb, nslots);

    gateup_all<<<dim3(704 + 22 * MAXSLOTS), dim3(256), 0, stream>>>(
        Xb, swtg, swtu, wtg, wtu, Ysh, Yr,
        slot_e, slot_rb, counts, nslots, tok_list, zerobuf);

    down_all<<<dim3(512 + 16 * MAXSLOTS * 2), dim3(256), 0, stream>>>(
        Ysh, Yr, swtd, wtd, out,
        slot_e, slot_rb, counts, nslots, tok_list, w_dense, sgate);
}

// Round 4
// 609.929 us; speedup vs baseline: 1.0477x; 1.0477x over previous
//
#include <hip/hip_runtime.h>
#include <hip/hip_bf16.h>

#define T_TOK 1024
#define HDIM  2048
#define NEXP  8
#define IDIM  1408
#define SIDIM 5632
#define MAXSLOTS 24

typedef __attribute__((ext_vector_type(8))) short bf16x8;
typedef __attribute__((ext_vector_type(4))) float f32x4;
typedef unsigned short ushort_t;

__device__ __forceinline__ unsigned f2bf(float x) {
    unsigned u = __float_as_uint(x);
    return (u + 0x7fffu + ((u >> 16) & 1u)) >> 16;
}
__device__ __forceinline__ unsigned pack2(float a, float b) {
    return f2bf(a) | (f2bf(b) << 16);
}
__device__ __forceinline__ void async16(const void* g, void* l) {
    __builtin_amdgcn_global_load_lds(
        (const __attribute__((address_space(1))) void*)g,
        (__attribute__((address_space(3))) void*)l, 16, 0, 0);
}

// Pipeline primitives: raw barrier (NO implicit vmcnt drain, unlike __syncthreads)
// + counted vmcnt waits + sched fences (rule #18: compiler doesn't model
// global_load_lds -> ds_read dependency, must pin ordering).
#define PIPE_BAR()    __builtin_amdgcn_s_barrier()
#define SCHED_FENCE() __builtin_amdgcn_sched_barrier(0)
#define WAIT_VM8()    asm volatile("s_waitcnt vmcnt(8)" ::: "memory")
#define WAIT_VM0()    asm volatile("s_waitcnt vmcnt(0)" ::: "memory")

// ---------------- Convert X: fp32 -> bf16 flat ----------------
__global__ __launch_bounds__(256) void conv_x(
    const float* __restrict__ src, ushort_t* __restrict__ dst)
{
    const int i = blockIdx.x * 256 + threadIdx.x;
    const float4* s = (const float4*)src + (size_t)i * 2;
    float4 a = s[0], b = s[1];
    union { ushort_t us[8]; uint4 v; } o;
    o.us[0] = (ushort_t)f2bf(a.x); o.us[1] = (ushort_t)f2bf(a.y);
    o.us[2] = (ushort_t)f2bf(a.z); o.us[3] = (ushort_t)f2bf(a.w);
    o.us[4] = (ushort_t)f2bf(b.x); o.us[5] = (ushort_t)f2bf(b.y);
    o.us[6] = (ushort_t)f2bf(b.z); o.us[7] = (ushort_t)f2bf(b.w);
    ((uint4*)dst)[i] = o.v;
}

// ------- Convert+transpose all weights: [K][N] f32 -> [N][K] bf16, one launch -------
// v3 layout (measured 0 bank conflicts): LDS [pair_row 32][68 words], XOR swizzle
//   word (P,col) at ldsw[P*68 + 4*((col>>2)^(P>>2)) + (col&3)].
__global__ __launch_bounds__(256) void conv_all(
    const float* __restrict__ wg, const float* __restrict__ wu,
    const float* __restrict__ wd, const float* __restrict__ swg,
    const float* __restrict__ swu, const float* __restrict__ swd,
    ushort_t* __restrict__ wtg, ushort_t* __restrict__ wtu,
    ushort_t* __restrict__ wtd, ushort_t* __restrict__ swtg,
    ushort_t* __restrict__ swtu, ushort_t* __restrict__ swtd)
{
    int id = blockIdx.x;
    const float* src; ushort_t* dst; int K, N, ktile, ntile;
    if (id < 11264) {
        const float* s0; ushort_t* d0;
        if (id < 5632) { s0 = wg; d0 = wtg; } else { s0 = wu; d0 = wtu; id -= 5632; }
        const int e = id / 704, t = id % 704;
        K = 2048; N = 1408;
        src = s0 + (size_t)e * K * N; dst = d0 + (size_t)e * K * N;
        ntile = t % 22; ktile = t / 22;
    } else if (id < 16896) {
        const int t2 = id - 11264;
        const int e = t2 / 704, t = t2 % 704;
        K = 1408; N = 2048;
        src = wd + (size_t)e * K * N; dst = wtd + (size_t)e * K * N;
        ntile = t % 32; ktile = t / 32;
    } else if (id < 22528) {
        int t2 = id - 16896; const float* s0; ushort_t* d0;
        if (t2 < 2816) { s0 = swg; d0 = swtg; } else { s0 = swu; d0 = swtu; t2 -= 2816; }
        K = 2048; N = 5632;
        src = s0; dst = d0;
        ntile = t2 % 88; ktile = t2 / 88;
    } else {
        const int t2 = id - 22528;
        K = 5632; N = 2048; src = swd; dst = swtd;
        ntile = t2 % 32; ktile = t2 / 32;
    }
    const int tid = threadIdx.x;
    __shared__ __align__(16) unsigned ldsw[32 * 68];
    const float* sp = src + (size_t)(ktile * 64) * N + ntile * 64;
    const int m = tid & 15;          // column group (16 groups x 4 cols)
    const int ph = tid >> 4;         // 0..15
#pragma unroll
    for (int h = 0; h < 2; ++h) {
        const int P = ph + h * 16;   // pair-row index 0..31
        const float* r0 = sp + (size_t)(2 * P) * N + m * 4;
        f32x4 a = __builtin_nontemporal_load((const f32x4*)r0);
        f32x4 b = __builtin_nontemporal_load((const f32x4*)(r0 + N));
        uint4 u;
        u.x = pack2(a[0], b[0]); u.y = pack2(a[1], b[1]);
        u.z = pack2(a[2], b[2]); u.w = pack2(a[3], b[3]);
        *(uint4*)&ldsw[P * 68 + 4 * (m ^ (P >> 2))] = u;
    }
    __syncthreads();
    ushort_t* dp = dst + (size_t)(ntile * 64) * K + ktile * 64;
#pragma unroll
    for (int j = 0; j < 2; ++j) {
        const int c = tid + j * 256;
        const int row = c >> 3, kc = c & 7;
        const int base = 4 * ((row >> 2) ^ kc) + (row & 3);
        uint4 v;
        v.x = ldsw[(4 * kc + 0) * 68 + base];
        v.y = ldsw[(4 * kc + 1) * 68 + base];
        v.z = ldsw[(4 * kc + 2) * 68 + base];
        v.w = ldsw[(4 * kc + 3) * 68 + base];
        *(uint4*)(dp + (size_t)row * K + kc * 8) = v;
    }
}

// ---------------- Router ----------------
__global__ __launch_bounds__(256) void router_kernel(
    const float* __restrict__ hs, const float* __restrict__ gw,
    const float* __restrict__ sgw, float* __restrict__ out_logits,
    float* __restrict__ w_dense, float* __restrict__ sgate,
    int* __restrict__ counts, int* __restrict__ tok_list)
{
    const int t = blockIdx.x;
    const int tid = threadIdx.x;
    const float* h = hs + (size_t)t * HDIM;
    float acc[9];
#pragma unroll
    for (int e = 0; e < 9; ++e) acc[e] = 0.f;
    for (int i = tid; i < HDIM; i += 256) {
        float hv = h[i];
        const float4* g4 = (const float4*)(gw + (size_t)i * NEXP);
        float4 g0 = g4[0], g1 = g4[1];
        acc[0] += hv * g0.x; acc[1] += hv * g0.y;
        acc[2] += hv * g0.z; acc[3] += hv * g0.w;
        acc[4] += hv * g1.x; acc[5] += hv * g1.y;
        acc[6] += hv * g1.z; acc[7] += hv * g1.w;
        acc[8] += hv * sgw[i];
    }
#pragma unroll
    for (int e = 0; e < 9; ++e)
        for (int off = 32; off > 0; off >>= 1)
            acc[e] += __shfl_down(acc[e], off, 64);
    __shared__ float lds[4][9];
    const int wid = tid >> 6, lane = tid & 63;
    if (lane == 0)
        for (int e = 0; e < 9; ++e) lds[wid][e] = acc[e];
    __syncthreads();
    if (tid == 0) {
        float l[9];
        for (int e = 0; e < 9; ++e)
            l[e] = lds[0][e] + lds[1][e] + lds[2][e] + lds[3][e];
        for (int e = 0; e < NEXP; ++e) out_logits[(size_t)t * NEXP + e] = l[e];
        float m = l[0];
        for (int e = 1; e < NEXP; ++e) m = fmaxf(m, l[e]);
        float p[NEXP], s = 0.f;
        for (int e = 0; e < NEXP; ++e) { p[e] = expf(l[e] - m); s += p[e]; }
        float inv = 1.f / s;
        for (int e = 0; e < NEXP; ++e) p[e] *= inv;
        int e0 = 0;
        for (int e = 1; e < NEXP; ++e) if (p[e] > p[e0]) e0 = e;
        int e1 = (e0 == 0) ? 1 : 0;
        for (int e = 0; e < NEXP; ++e) if (e != e0 && p[e] > p[e1]) e1 = e;
        for (int e = 0; e < NEXP; ++e)
            w_dense[(size_t)t * NEXP + e] = (e == e0) ? p[e0] : ((e == e1) ? p[e1] : 0.f);
        sgate[t] = 1.f / (1.f + expf(-l[8]));
        int p0 = atomicAdd(&counts[e0], 1); tok_list[e0 * T_TOK + p0] = t;
        int p1 = atomicAdd(&counts[e1], 1); tok_list[e1 * T_TOK + p1] = t;
    }
}

__global__ __launch_bounds__(64) void slot_kernel(
    const int* __restrict__ counts, int* __restrict__ slot_e,
    int* __restrict__ slot_rb, int* __restrict__ nslots)
{
    if (threadIdx.x == 0 && blockIdx.x == 0) {
        int ns = 0;
        for (int e = 0; e < NEXP; ++e)
            for (int b = 0; b < counts[e]; b += 128) {
                slot_e[ns] = e; slot_rb[ns] = b; ++ns;
            }
        nslots[0] = ns;
    }
}

// ---- Gate+Up merged (shared + routed): block 128M x 64N(x2 mats), BK=64 ----
// v5: counted-vmcnt pipeline. Per tile: vmcnt(8) [tile t's 8 loads landed,
// tile t+1's 8 stay in flight]; raw s_barrier; compute(t); s_barrier;
// stage(t+2 -> just-consumed buffer). Never drains vmcnt to 0 in main loop.
__global__ __launch_bounds__(256) void gateup_all(
    const ushort_t* __restrict__ Xb,
    const ushort_t* __restrict__ swtg, const ushort_t* __restrict__ swtu,
    const ushort_t* __restrict__ wtg, const ushort_t* __restrict__ wtu,
    ushort_t* __restrict__ Ysh, ushort_t* __restrict__ Yr,
    const int* __restrict__ slot_e, const int* __restrict__ slot_rb,
    const int* __restrict__ counts, const int* __restrict__ nslots,
    const int* __restrict__ tok_list, const ushort_t* __restrict__ zerobuf)
{
    const int id = blockIdx.x;
    int n0, slot, e, rowbase, N, mode;
    if (id < 704) {
        mode = 1; n0 = (id % 88) * 64; slot = id / 88; e = 0; rowbase = 0; N = SIDIM;
    } else {
        mode = 0;
        const int id2 = id - 704;
        n0 = (id2 % 22) * 64; slot = id2 / 22;
        if (slot >= nslots[0]) return;
        e = slot_e[slot]; rowbase = slot_rb[slot]; N = IDIM;
    }
    const ushort_t* __restrict__ Wg = mode ? swtg : wtg + (size_t)e * HDIM * IDIM;
    const ushort_t* __restrict__ Wu = mode ? swtu : wtu + (size_t)e * HDIM * IDIM;
    ushort_t* __restrict__ Y = mode ? Ysh : Yr;
    const int K = HDIM;

    const int tid = threadIdx.x, lane = tid & 63, wid = tid >> 6;
    const int wr = (wid >> 1) * 64;
    const int wc = (wid & 1) * 32;
    const int fm = lane & 15, kg = lane >> 4;

    __shared__ int ltok[128];
    __shared__ __align__(16) ushort_t Xa[2][128 * 64];
    __shared__ __align__(16) ushort_t Bgs[2][64 * 64];
    __shared__ __align__(16) ushort_t Bus[2][64 * 64];

    if (tid < 128) {
        int tg;
        if (mode == 0) {
            int cnt = counts[e];
            tg = (rowbase + tid < cnt) ? tok_list[e * T_TOK + rowbase + tid] : -1;
        } else {
            tg = slot * 128 + tid;
        }
        ltok[tid] = tg;
    }
    __syncthreads();

    f32x4 ag[4][2], au[4][2];
#pragma unroll
    for (int a = 0; a < 4; ++a)
#pragma unroll
        for (int b = 0; b < 2; ++b) {
            ag[a][b] = f32x4{0.f, 0.f, 0.f, 0.f};
            au[a][b] = f32x4{0.f, 0.f, 0.f, 0.f};
        }

    // per-thread swizzled k-offset (same for every issue)
    const int koff = (((tid & 7) ^ ((tid >> 3) & 7))) * 8;
    const ushort_t* pA[4];
#pragma unroll
    for (int j = 0; j < 4; ++j) {
        const int r = (tid >> 3) + j * 32;
        const int tk = ltok[r];
        pA[j] = (tk >= 0) ? Xb + (size_t)tk * K + koff : zerobuf;
    }
    const ushort_t* pG[2];
    const ushort_t* pU[2];
#pragma unroll
    for (int j = 0; j < 2; ++j) {
        const int r = (tid >> 3) + j * 32;
        pG[j] = Wg + (size_t)(n0 + r) * K + koff;
        pU[j] = Wu + (size_t)(n0 + r) * K + koff;
    }

// 8 loads per wave per STAGE (4 A + 2 G + 2 U), fixed order for FIFO vmcnt.
#define GU_STAGE(xp, gp, up, k0)                                            \
    {                                                                       \
        _Pragma("unroll")                                                   \
        for (int j = 0; j < 4; ++j)                                         \
            async16(pA[j] + (k0), &(xp)[(j * 256 + wid * 64) * 8]);         \
        _Pragma("unroll")                                                   \
        for (int j = 0; j < 2; ++j) {                                       \
            async16(pG[j] + (k0), &(gp)[(j * 256 + wid * 64) * 8]);         \
            async16(pU[j] + (k0), &(up)[(j * 256 + wid * 64) * 8]);         \
        }                                                                   \
    }

#define GU_COMP(xa, bg, bu)                                                 \
    {                                                                       \
        _Pragma("unroll")                                                   \
        for (int ks = 0; ks < 2; ++ks) {                                    \
            const int kx = ((ks * 4 + kg) ^ (fm & 7)) * 8;                  \
            bf16x8 af[4];                                                   \
            _Pragma("unroll")                                               \
            for (int mt = 0; mt < 4; ++mt)                                  \
                af[mt] = *(const bf16x8*)&(xa)[(wr + mt * 16 + fm) * 64 + kx]; \
            _Pragma("unroll")                                               \
            for (int nt = 0; nt < 2; ++nt) {                                \
                const int rb = (wc + nt * 16 + fm) * 64 + kx;               \
                bf16x8 bgv = *(const bf16x8*)&(bg)[rb];                     \
                bf16x8 buv = *(const bf16x8*)&(bu)[rb];                     \
                _Pragma("unroll")                                           \
                for (int mt = 0; mt < 4; ++mt) {                            \
                    ag[mt][nt] = __builtin_amdgcn_mfma_f32_16x16x32_bf16(af[mt], bgv, ag[mt][nt], 0, 0, 0); \
                    au[mt][nt] = __builtin_amdgcn_mfma_f32_16x16x32_bf16(af[mt], buv, au[mt][nt], 0, 0, 0); \
                }                                                           \
            }                                                               \
        }                                                                   \
    }

    const int NT = K / 64;  // 32 (even)
    GU_STAGE(Xa[0], Bgs[0], Bus[0], 0);
    GU_STAGE(Xa[1], Bgs[1], Bus[1], 64);

    int t = 0;
    for (; t + 3 < NT; t += 2) {
        WAIT_VM8(); PIPE_BAR(); SCHED_FENCE();
        GU_COMP(Xa[0], Bgs[0], Bus[0]);
        SCHED_FENCE(); PIPE_BAR(); SCHED_FENCE();
        GU_STAGE(Xa[0], Bgs[0], Bus[0], (t + 2) * 64);

        WAIT_VM8(); PIPE_BAR(); SCHED_FENCE();
        GU_COMP(Xa[1], Bgs[1], Bus[1]);
        SCHED_FENCE(); PIPE_BAR(); SCHED_FENCE();
        GU_STAGE(Xa[1], Bgs[1], Bus[1], (t + 3) * 64);
    }
    if (t + 2 < NT) {   // odd NT tail
        WAIT_VM8(); PIPE_BAR(); SCHED_FENCE();
        GU_COMP(Xa[0], Bgs[0], Bus[0]);
        SCHED_FENCE(); PIPE_BAR(); SCHED_FENCE();
        GU_STAGE(Xa[0], Bgs[0], Bus[0], (t + 2) * 64);
        WAIT_VM8(); PIPE_BAR(); SCHED_FENCE();
        GU_COMP(Xa[1], Bgs[1], Bus[1]);
        WAIT_VM0(); PIPE_BAR(); SCHED_FENCE();
        GU_COMP(Xa[0], Bgs[0], Bus[0]);
    } else {            // even NT tail
        WAIT_VM8(); PIPE_BAR(); SCHED_FENCE();
        GU_COMP(Xa[0], Bgs[0], Bus[0]);
        WAIT_VM0(); PIPE_BAR(); SCHED_FENCE();
        GU_COMP(Xa[1], Bgs[1], Bus[1]);
    }
#undef GU_STAGE
#undef GU_COMP

#pragma unroll
    for (int mt = 0; mt < 4; ++mt)
#pragma unroll
        for (int nt = 0; nt < 2; ++nt) {
            const int col = n0 + wc + nt * 16 + fm;
#pragma unroll
            for (int i = 0; i < 4; ++i) {
                const int row = wr + mt * 16 + kg * 4 + i;
                float g = ag[mt][nt][i], u = au[mt][nt][i];
                float yv = g / (1.f + expf(-g)) * u;
                Y[(size_t)(slot * 128 + row) * N + col] = (ushort_t)f2bf(yv);
            }
        }
}

// ---- Down merged (shared z-split 4 + routed z-split 2): 128M x 128N, BK=64 ----
// v5: same counted-vmcnt pipeline as gateup_all.
__global__ __launch_bounds__(256) void down_all(
    const ushort_t* __restrict__ Ysh, const ushort_t* __restrict__ Yr,
    const ushort_t* __restrict__ swtd, const ushort_t* __restrict__ wtd,
    float* __restrict__ out,
    const int* __restrict__ slot_e, const int* __restrict__ slot_rb,
    const int* __restrict__ counts, const int* __restrict__ nslots,
    const int* __restrict__ tok_list, const float* __restrict__ w_dense,
    const float* __restrict__ sgate)
{
    const int id = blockIdx.x;
    int n0, slot, e, rowbase, K, kbase, ksteps, mode;
    const ushort_t* Yb;
    const ushort_t* Wd;
    if (id < 512) {
        mode = 1;
        n0 = (id & 15) * 128; slot = (id >> 4) & 7;
        const int z = id >> 7;
        K = SIDIM; kbase = z * 1408; ksteps = 22;
        e = 0; rowbase = 0;
        Yb = Ysh + (size_t)slot * 128 * K;
        Wd = swtd;
    } else {
        mode = 0;
        const int id2 = id - 512;
        n0 = (id2 & 15) * 128;
        const int rest = id2 >> 4;
        slot = rest >> 1;
        if (slot >= nslots[0]) return;
        const int z = rest & 1;
        K = IDIM; kbase = z * 704; ksteps = 11;
        e = slot_e[slot]; rowbase = slot_rb[slot];
        Yb = Yr + (size_t)slot * 128 * K;
        Wd = wtd + (size_t)e * IDIM * HDIM;
    }
    const int tid = threadIdx.x, lane = tid & 63, wid = tid >> 6;
    const int wr = (wid >> 1) * 64;
    const int wc = (wid & 1) * 64;
    const int fm = lane & 15, kg = lane >> 4;

    __shared__ int ltok[128];
    __shared__ float lw[128];
    __shared__ __align__(16) ushort_t Ya[2][128 * 64];
    __shared__ __align__(16) ushort_t Bd[2][128 * 64];

    if (tid < 128) {
        int tg; float wv;
        if (mode == 0) {
            int cnt = counts[e];
            if (rowbase + tid < cnt) {
                tg = tok_list[e * T_TOK + rowbase + tid];
                wv = w_dense[(size_t)tg * NEXP + e];
            } else { tg = -1; wv = 0.f; }
        } else {
            tg = slot * 128 + tid; wv = sgate[tg];
        }
        ltok[tid] = tg; lw[tid] = wv;
    }
    __syncthreads();

    f32x4 acc[4][4];
#pragma unroll
    for (int a = 0; a < 4; ++a)
#pragma unroll
        for (int b = 0; b < 4; ++b) acc[a][b] = f32x4{0.f, 0.f, 0.f, 0.f};

    const int koff = (((tid & 7) ^ ((tid >> 3) & 7))) * 8;
    const ushort_t* pY[4];
    const ushort_t* pW[4];
#pragma unroll
    for (int j = 0; j < 4; ++j) {
        const int r = (tid >> 3) + j * 32;
        pY[j] = Yb + (size_t)r * K + kbase + koff;
        pW[j] = Wd + (size_t)(n0 + r) * K + kbase + koff;
    }

// 8 loads per wave per STAGE (4 Y + 4 W), fixed order for FIFO vmcnt.
#define D_STAGE(yp, bp, k0)                                                 \
    {                                                                       \
        _Pragma("unroll")                                                   \
        for (int j = 0; j < 4; ++j) {                                       \
            async16(pY[j] + (k0), &(yp)[(j * 256 + wid * 64) * 8]);         \
            async16(pW[j] + (k0), &(bp)[(j * 256 + wid * 64) * 8]);         \
        }                                                                   \
    }

#define D_COMP(ya, bd)                                                      \
    {                                                                       \
        _Pragma("unroll")                                                   \
        for (int ks = 0; ks < 2; ++ks) {                                    \
            const int kx = ((ks * 4 + kg) ^ (fm & 7)) * 8;                  \
            bf16x8 af[4];                                                   \
            _Pragma("unroll")                                               \
            for (int mt = 0; mt < 4; ++mt)                                  \
                af[mt] = *(const bf16x8*)&(ya)[(wr + mt * 16 + fm) * 64 + kx]; \
            _Pragma("unroll")                                               \
            for (int nt = 0; nt < 4; ++nt) {                                \
                bf16x8 bfv = *(const bf16x8*)&(bd)[(wc + nt * 16 + fm) * 64 + kx]; \
                _Pragma("unroll")                                           \
                for (int mt = 0; mt < 4; ++mt)                              \
                    acc[mt][nt] = __builtin_amdgcn_mfma_f32_16x16x32_bf16(af[mt], bfv, acc[mt][nt], 0, 0, 0); \
            }                                                               \
        }                                                                   \
    }

    const int NT = ksteps;  // 22 (even) or 11 (odd)
    D_STAGE(Ya[0], Bd[0], 0);
    D_STAGE(Ya[1], Bd[1], 64);

    int t = 0;
    for (; t + 3 < NT; t += 2) {
        WAIT_VM8(); PIPE_BAR(); SCHED_FENCE();
        D_COMP(Ya[0], Bd[0]);
        SCHED_FENCE(); PIPE_BAR(); SCHED_FENCE();
        D_STAGE(Ya[0], Bd[0], (t + 2) * 64);

        WAIT_VM8(); PIPE_BAR(); SCHED_FENCE();
        D_COMP(Ya[1], Bd[1]);
        SCHED_FENCE(); PIPE_BAR(); SCHED_FENCE();
        D_STAGE(Ya[1], Bd[1], (t + 3) * 64);
    }
    if (t + 2 < NT) {   // odd NT tail (routed ksteps=11)
        WAIT_VM8(); PIPE_BAR(); SCHED_FENCE();
        D_COMP(Ya[0], Bd[0]);
        SCHED_FENCE(); PIPE_BAR(); SCHED_FENCE();
        D_STAGE(Ya[0], Bd[0], (t + 2) * 64);
        WAIT_VM8(); PIPE_BAR(); SCHED_FENCE();
        D_COMP(Ya[1], Bd[1]);
        WAIT_VM0(); PIPE_BAR(); SCHED_FENCE();
        D_COMP(Ya[0], Bd[0]);
    } else {            // even NT tail (shared ksteps=22)
        WAIT_VM8(); PIPE_BAR(); SCHED_FENCE();
        D_COMP(Ya[0], Bd[0]);
        WAIT_VM0(); PIPE_BAR(); SCHED_FENCE();
        D_COMP(Ya[1], Bd[1]);
    }
#undef D_STAGE
#undef D_COMP

#pragma unroll
    for (int mt = 0; mt < 4; ++mt)
#pragma unroll
        for (int nt = 0; nt < 4; ++nt) {
            const int col = n0 + wc + nt * 16 + fm;
#pragma unroll
            for (int i = 0; i < 4; ++i) {
                const int row = wr + mt * 16 + kg * 4 + i;
                const int tg = ltok[row];
                if (tg >= 0)
                    atomicAdd(out + (size_t)tg * HDIM + col, lw[row] * acc[mt][nt][i]);
            }
        }
}

extern "C" void kernel_launch(void* const* d_in, const int* in_sizes, int n_in,
                              void* d_out, int out_size, void* d_ws, size_t ws_size,
                              hipStream_t stream)
{
    const float* hs  = (const float*)d_in[0];
    const float* gw  = (const float*)d_in[1];
    const float* wg  = (const float*)d_in[2];
    const float* wu  = (const float*)d_in[3];
    const float* wd  = (const float*)d_in[4];
    const float* swg = (const float*)d_in[5];
    const float* swu = (const float*)d_in[6];
    const float* swd = (const float*)d_in[7];
    const float* sgw = (const float*)d_in[8];
    float* out = (float*)d_out;
    char* ws = (char*)d_ws;

    float* w_dense      = (float*)(ws + 0x00000);
    float* sgate        = (float*)(ws + 0x08000);
    int* counts         = (int*)(ws + 0x09000);
    int* nslots         = (int*)(ws + 0x09100);
    int* slot_e         = (int*)(ws + 0x09200);
    int* slot_rb        = (int*)(ws + 0x09300);
    int* tok_list       = (int*)(ws + 0x09400);
    ushort_t* zerobuf   = (ushort_t*)(ws + 0x11400);   // 16 KB zeros
    ushort_t* Xb        = (ushort_t*)(ws + 0x20000);
    ushort_t* Yr        = (ushort_t*)(ws + 0x420000);
    ushort_t* Ysh       = (ushort_t*)(ws + 0xC60000);
    ushort_t* wtg       = (ushort_t*)(ws + 0x1760000);
    ushort_t* wtu       = (ushort_t*)(ws + 0x4360000);
    ushort_t* wtd       = (ushort_t*)(ws + 0x6F60000);
    ushort_t* swtg      = (ushort_t*)(ws + 0x9B60000);
    ushort_t* swtu      = (ushort_t*)(ws + 0xB160000);
    ushort_t* swtd      = (ushort_t*)(ws + 0xC760000);
    float* out_logits = out + (size_t)T_TOK * HDIM;

    hipMemsetAsync(counts, 0, 256, stream);
    hipMemsetAsync(zerobuf, 0, 16384, stream);
    hipMemsetAsync(out, 0, (size_t)T_TOK * HDIM * sizeof(float), stream);

    conv_x<<<dim3(1024), dim3(256), 0, stream>>>(hs, Xb);
    conv_all<<<dim3(25344), dim3(256), 0, stream>>>(
        wg, wu, wd, swg, swu, swd, wtg, wtu, wtd, swtg, swtu, swtd);

    router_kernel<<<dim3(T_TOK), dim3(256), 0, stream>>>(
        hs, gw, sgw, out_logits, w_dense, sgate, counts, tok_list);
    slot_kernel<<<dim3(1), dim3(64), 0, stream>>>(counts, slot_e, slot_rb, nslots);

    gateup_all<<<dim3(704 + 22 * MAXSLOTS), dim3(256), 0, stream>>>(
        Xb, swtg, swtu, wtg, wtu, Ysh, Yr,
        slot_e, slot_rb, counts, nslots, tok_list, zerobuf);

    down_all<<<dim3(512 + 16 * MAXSLOTS * 2), dim3(256), 0, stream>>>(
        Ysh, Yr, swtd, wtd, out,
        slot_e, slot_rb, counts, nslots, tok_list, w_dense, sgate);
}

// Round 5
// 573.026 us; speedup vs baseline: 1.1152x; 1.0644x over previous
//
#include <hip/hip_runtime.h>
#include <hip/hip_bf16.h>

#define T_TOK 1024
#define HDIM  2048
#define NEXP  8
#define IDIM  1408
#define SIDIM 5632
#define MAXSLOTS 24

typedef __attribute__((ext_vector_type(8))) short bf16x8;
typedef __attribute__((ext_vector_type(4))) float f32x4;
typedef unsigned short ushort_t;

__device__ __forceinline__ unsigned f2bf(float x) {
    unsigned u = __float_as_uint(x);
    return (u + 0x7fffu + ((u >> 16) & 1u)) >> 16;
}
__device__ __forceinline__ unsigned pack2(float a, float b) {
    return f2bf(a) | (f2bf(b) << 16);
}
__device__ __forceinline__ void async16(const void* g, void* l) {
    __builtin_amdgcn_global_load_lds(
        (const __attribute__((address_space(1))) void*)g,
        (__attribute__((address_space(3))) void*)l, 16, 0, 0);
}

// Pipeline primitives (gateup v5): raw barrier + counted vmcnt + sched fences.
#define PIPE_BAR()    __builtin_amdgcn_s_barrier()
#define SCHED_FENCE() __builtin_amdgcn_sched_barrier(0)
#define WAIT_VM8()    asm volatile("s_waitcnt vmcnt(8)" ::: "memory")
#define WAIT_VM0()    asm volatile("s_waitcnt vmcnt(0)" ::: "memory")

// ---------------- Convert X: fp32 -> bf16 flat ----------------
__global__ __launch_bounds__(256) void conv_x(
    const float* __restrict__ src, ushort_t* __restrict__ dst)
{
    const int i = blockIdx.x * 256 + threadIdx.x;
    const float4* s = (const float4*)src + (size_t)i * 2;
    float4 a = s[0], b = s[1];
    union { ushort_t us[8]; uint4 v; } o;
    o.us[0] = (ushort_t)f2bf(a.x); o.us[1] = (ushort_t)f2bf(a.y);
    o.us[2] = (ushort_t)f2bf(a.z); o.us[3] = (ushort_t)f2bf(a.w);
    o.us[4] = (ushort_t)f2bf(b.x); o.us[5] = (ushort_t)f2bf(b.y);
    o.us[6] = (ushort_t)f2bf(b.z); o.us[7] = (ushort_t)f2bf(b.w);
    ((uint4*)dst)[i] = o.v;
}

// ------- Convert+transpose all weights: [K][N] f32 -> [N][K] bf16, one launch -------
// v3 layout (measured 0 bank conflicts): LDS [pair_row 32][68 words], XOR swizzle
//   word (P,col) at ldsw[P*68 + 4*((col>>2)^(P>>2)) + (col&3)].
__global__ __launch_bounds__(256) void conv_all(
    const float* __restrict__ wg, const float* __restrict__ wu,
    const float* __restrict__ wd, const float* __restrict__ swg,
    const float* __restrict__ swu, const float* __restrict__ swd,
    ushort_t* __restrict__ wtg, ushort_t* __restrict__ wtu,
    ushort_t* __restrict__ wtd, ushort_t* __restrict__ swtg,
    ushort_t* __restrict__ swtu, ushort_t* __restrict__ swtd)
{
    int id = blockIdx.x;
    const float* src; ushort_t* dst; int K, N, ktile, ntile;
    if (id < 11264) {
        const float* s0; ushort_t* d0;
        if (id < 5632) { s0 = wg; d0 = wtg; } else { s0 = wu; d0 = wtu; id -= 5632; }
        const int e = id / 704, t = id % 704;
        K = 2048; N = 1408;
        src = s0 + (size_t)e * K * N; dst = d0 + (size_t)e * K * N;
        ntile = t % 22; ktile = t / 22;
    } else if (id < 16896) {
        const int t2 = id - 11264;
        const int e = t2 / 704, t = t2 % 704;
        K = 1408; N = 2048;
        src = wd + (size_t)e * K * N; dst = wtd + (size_t)e * K * N;
        ntile = t % 32; ktile = t / 32;
    } else if (id < 22528) {
        int t2 = id - 16896; const float* s0; ushort_t* d0;
        if (t2 < 2816) { s0 = swg; d0 = swtg; } else { s0 = swu; d0 = swtu; t2 -= 2816; }
        K = 2048; N = 5632;
        src = s0; dst = d0;
        ntile = t2 % 88; ktile = t2 / 88;
    } else {
        const int t2 = id - 22528;
        K = 5632; N = 2048; src = swd; dst = swtd;
        ntile = t2 % 32; ktile = t2 / 32;
    }
    const int tid = threadIdx.x;
    __shared__ __align__(16) unsigned ldsw[32 * 68];
    const float* sp = src + (size_t)(ktile * 64) * N + ntile * 64;
    const int m = tid & 15;          // column group (16 groups x 4 cols)
    const int ph = tid >> 4;         // 0..15
#pragma unroll
    for (int h = 0; h < 2; ++h) {
        const int P = ph + h * 16;   // pair-row index 0..31
        const float* r0 = sp + (size_t)(2 * P) * N + m * 4;
        f32x4 a = __builtin_nontemporal_load((const f32x4*)r0);
        f32x4 b = __builtin_nontemporal_load((const f32x4*)(r0 + N));
        uint4 u;
        u.x = pack2(a[0], b[0]); u.y = pack2(a[1], b[1]);
        u.z = pack2(a[2], b[2]); u.w = pack2(a[3], b[3]);
        *(uint4*)&ldsw[P * 68 + 4 * (m ^ (P >> 2))] = u;
    }
    __syncthreads();
    ushort_t* dp = dst + (size_t)(ntile * 64) * K + ktile * 64;
#pragma unroll
    for (int j = 0; j < 2; ++j) {
        const int c = tid + j * 256;
        const int row = c >> 3, kc = c & 7;
        const int base = 4 * ((row >> 2) ^ kc) + (row & 3);
        uint4 v;
        v.x = ldsw[(4 * kc + 0) * 68 + base];
        v.y = ldsw[(4 * kc + 1) * 68 + base];
        v.z = ldsw[(4 * kc + 2) * 68 + base];
        v.w = ldsw[(4 * kc + 3) * 68 + base];
        *(uint4*)(dp + (size_t)row * K + kc * 8) = v;
    }
}

// ---------------- Router ----------------
// v6: also records per-token (expert,pos) pairs + weights for atomic-free combine.
__global__ __launch_bounds__(256) void router_kernel(
    const float* __restrict__ hs, const float* __restrict__ gw,
    const float* __restrict__ sgw, float* __restrict__ out_logits,
    float* __restrict__ aw, int* __restrict__ apos,
    float* __restrict__ sgate,
    int* __restrict__ counts, int* __restrict__ tok_list)
{
    const int t = blockIdx.x;
    const int tid = threadIdx.x;
    const float* h = hs + (size_t)t * HDIM;
    float acc[9];
#pragma unroll
    for (int e = 0; e < 9; ++e) acc[e] = 0.f;
    for (int i = tid; i < HDIM; i += 256) {
        float hv = h[i];
        const float4* g4 = (const float4*)(gw + (size_t)i * NEXP);
        float4 g0 = g4[0], g1 = g4[1];
        acc[0] += hv * g0.x; acc[1] += hv * g0.y;
        acc[2] += hv * g0.z; acc[3] += hv * g0.w;
        acc[4] += hv * g1.x; acc[5] += hv * g1.y;
        acc[6] += hv * g1.z; acc[7] += hv * g1.w;
        acc[8] += hv * sgw[i];
    }
#pragma unroll
    for (int e = 0; e < 9; ++e)
        for (int off = 32; off > 0; off >>= 1)
            acc[e] += __shfl_down(acc[e], off, 64);
    __shared__ float lds[4][9];
    const int wid = tid >> 6, lane = tid & 63;
    if (lane == 0)
        for (int e = 0; e < 9; ++e) lds[wid][e] = acc[e];
    __syncthreads();
    if (tid == 0) {
        float l[9];
        for (int e = 0; e < 9; ++e)
            l[e] = lds[0][e] + lds[1][e] + lds[2][e] + lds[3][e];
        for (int e = 0; e < NEXP; ++e) out_logits[(size_t)t * NEXP + e] = l[e];
        float m = l[0];
        for (int e = 1; e < NEXP; ++e) m = fmaxf(m, l[e]);
        float p[NEXP], s = 0.f;
        for (int e = 0; e < NEXP; ++e) { p[e] = expf(l[e] - m); s += p[e]; }
        float inv = 1.f / s;
        for (int e = 0; e < NEXP; ++e) p[e] *= inv;
        int e0 = 0;
        for (int e = 1; e < NEXP; ++e) if (p[e] > p[e0]) e0 = e;
        int e1 = (e0 == 0) ? 1 : 0;
        for (int e = 0; e < NEXP; ++e) if (e != e0 && p[e] > p[e1]) e1 = e;
        sgate[t] = 1.f / (1.f + expf(-l[8]));
        int p0 = atomicAdd(&counts[e0], 1); tok_list[e0 * T_TOK + p0] = t;
        int p1 = atomicAdd(&counts[e1], 1); tok_list[e1 * T_TOK + p1] = t;
        aw[t * 2]     = p[e0];
        aw[t * 2 + 1] = p[e1];
        apos[t * 2]     = (e0 << 10) | p0;
        apos[t * 2 + 1] = (e1 << 10) | p1;
    }
}

__global__ __launch_bounds__(64) void slot_kernel(
    const int* __restrict__ counts, int* __restrict__ slot_e,
    int* __restrict__ slot_rb, int* __restrict__ nslots,
    int* __restrict__ sbase)
{
    if (threadIdx.x == 0 && blockIdx.x == 0) {
        int ns = 0;
        for (int e = 0; e < NEXP; ++e) {
            sbase[e] = ns;
            for (int b = 0; b < counts[e]; b += 128) {
                slot_e[ns] = e; slot_rb[ns] = b; ++ns;
            }
        }
        nslots[0] = ns;
    }
}

// ---- Gate+Up merged (shared + routed): block 128M x 64N(x2 mats), BK=64 ----
// v5: counted-vmcnt pipeline (kept from R4).
__global__ __launch_bounds__(256) void gateup_all(
    const ushort_t* __restrict__ Xb,
    const ushort_t* __restrict__ swtg, const ushort_t* __restrict__ swtu,
    const ushort_t* __restrict__ wtg, const ushort_t* __restrict__ wtu,
    ushort_t* __restrict__ Ysh, ushort_t* __restrict__ Yr,
    const int* __restrict__ slot_e, const int* __restrict__ slot_rb,
    const int* __restrict__ counts, const int* __restrict__ nslots,
    const int* __restrict__ tok_list, const ushort_t* __restrict__ zerobuf)
{
    const int id = blockIdx.x;
    int n0, slot, e, rowbase, N, mode;
    if (id < 704) {
        mode = 1; n0 = (id % 88) * 64; slot = id / 88; e = 0; rowbase = 0; N = SIDIM;
    } else {
        mode = 0;
        const int id2 = id - 704;
        n0 = (id2 % 22) * 64; slot = id2 / 22;
        if (slot >= nslots[0]) return;
        e = slot_e[slot]; rowbase = slot_rb[slot]; N = IDIM;
    }
    const ushort_t* __restrict__ Wg = mode ? swtg : wtg + (size_t)e * HDIM * IDIM;
    const ushort_t* __restrict__ Wu = mode ? swtu : wtu + (size_t)e * HDIM * IDIM;
    ushort_t* __restrict__ Y = mode ? Ysh : Yr;
    const int K = HDIM;

    const int tid = threadIdx.x, lane = tid & 63, wid = tid >> 6;
    const int wr = (wid >> 1) * 64;
    const int wc = (wid & 1) * 32;
    const int fm = lane & 15, kg = lane >> 4;

    __shared__ int ltok[128];
    __shared__ __align__(16) ushort_t Xa[2][128 * 64];
    __shared__ __align__(16) ushort_t Bgs[2][64 * 64];
    __shared__ __align__(16) ushort_t Bus[2][64 * 64];

    if (tid < 128) {
        int tg;
        if (mode == 0) {
            int cnt = counts[e];
            tg = (rowbase + tid < cnt) ? tok_list[e * T_TOK + rowbase + tid] : -1;
        } else {
            tg = slot * 128 + tid;
        }
        ltok[tid] = tg;
    }
    __syncthreads();

    f32x4 ag[4][2], au[4][2];
#pragma unroll
    for (int a = 0; a < 4; ++a)
#pragma unroll
        for (int b = 0; b < 2; ++b) {
            ag[a][b] = f32x4{0.f, 0.f, 0.f, 0.f};
            au[a][b] = f32x4{0.f, 0.f, 0.f, 0.f};
        }

    const int koff = (((tid & 7) ^ ((tid >> 3) & 7))) * 8;
    const ushort_t* pA[4];
#pragma unroll
    for (int j = 0; j < 4; ++j) {
        const int r = (tid >> 3) + j * 32;
        const int tk = ltok[r];
        pA[j] = (tk >= 0) ? Xb + (size_t)tk * K + koff : zerobuf;
    }
    const ushort_t* pG[2];
    const ushort_t* pU[2];
#pragma unroll
    for (int j = 0; j < 2; ++j) {
        const int r = (tid >> 3) + j * 32;
        pG[j] = Wg + (size_t)(n0 + r) * K + koff;
        pU[j] = Wu + (size_t)(n0 + r) * K + koff;
    }

#define GU_STAGE(xp, gp, up, k0)                                            \
    {                                                                       \
        _Pragma("unroll")                                                   \
        for (int j = 0; j < 4; ++j)                                         \
            async16(pA[j] + (k0), &(xp)[(j * 256 + wid * 64) * 8]);         \
        _Pragma("unroll")                                                   \
        for (int j = 0; j < 2; ++j) {                                       \
            async16(pG[j] + (k0), &(gp)[(j * 256 + wid * 64) * 8]);         \
            async16(pU[j] + (k0), &(up)[(j * 256 + wid * 64) * 8]);         \
        }                                                                   \
    }

#define GU_COMP(xa, bg, bu)                                                 \
    {                                                                       \
        _Pragma("unroll")                                                   \
        for (int ks = 0; ks < 2; ++ks) {                                    \
            const int kx = ((ks * 4 + kg) ^ (fm & 7)) * 8;                  \
            bf16x8 af[4];                                                   \
            _Pragma("unroll")                                               \
            for (int mt = 0; mt < 4; ++mt)                                  \
                af[mt] = *(const bf16x8*)&(xa)[(wr + mt * 16 + fm) * 64 + kx]; \
            _Pragma("unroll")                                               \
            for (int nt = 0; nt < 2; ++nt) {                                \
                const int rb = (wc + nt * 16 + fm) * 64 + kx;               \
                bf16x8 bgv = *(const bf16x8*)&(bg)[rb];                     \
                bf16x8 buv = *(const bf16x8*)&(bu)[rb];                     \
                _Pragma("unroll")                                           \
                for (int mt = 0; mt < 4; ++mt) {                            \
                    ag[mt][nt] = __builtin_amdgcn_mfma_f32_16x16x32_bf16(af[mt], bgv, ag[mt][nt], 0, 0, 0); \
                    au[mt][nt] = __builtin_amdgcn_mfma_f32_16x16x32_bf16(af[mt], buv, au[mt][nt], 0, 0, 0); \
                }                                                           \
            }                                                               \
        }                                                                   \
    }

    const int NT = K / 64;  // 32 (even)
    GU_STAGE(Xa[0], Bgs[0], Bus[0], 0);
    GU_STAGE(Xa[1], Bgs[1], Bus[1], 64);

    int t = 0;
    for (; t + 3 < NT; t += 2) {
        WAIT_VM8(); PIPE_BAR(); SCHED_FENCE();
        GU_COMP(Xa[0], Bgs[0], Bus[0]);
        SCHED_FENCE(); PIPE_BAR(); SCHED_FENCE();
        GU_STAGE(Xa[0], Bgs[0], Bus[0], (t + 2) * 64);

        WAIT_VM8(); PIPE_BAR(); SCHED_FENCE();
        GU_COMP(Xa[1], Bgs[1], Bus[1]);
        SCHED_FENCE(); PIPE_BAR(); SCHED_FENCE();
        GU_STAGE(Xa[1], Bgs[1], Bus[1], (t + 3) * 64);
    }
    if (t + 2 < NT) {   // odd NT tail
        WAIT_VM8(); PIPE_BAR(); SCHED_FENCE();
        GU_COMP(Xa[0], Bgs[0], Bus[0]);
        SCHED_FENCE(); PIPE_BAR(); SCHED_FENCE();
        GU_STAGE(Xa[0], Bgs[0], Bus[0], (t + 2) * 64);
        WAIT_VM8(); PIPE_BAR(); SCHED_FENCE();
        GU_COMP(Xa[1], Bgs[1], Bus[1]);
        WAIT_VM0(); PIPE_BAR(); SCHED_FENCE();
        GU_COMP(Xa[0], Bgs[0], Bus[0]);
    } else {            // even NT tail
        WAIT_VM8(); PIPE_BAR(); SCHED_FENCE();
        GU_COMP(Xa[0], Bgs[0], Bus[0]);
        WAIT_VM0(); PIPE_BAR(); SCHED_FENCE();
        GU_COMP(Xa[1], Bgs[1], Bus[1]);
    }
#undef GU_STAGE
#undef GU_COMP

#pragma unroll
    for (int mt = 0; mt < 4; ++mt)
#pragma unroll
        for (int nt = 0; nt < 2; ++nt) {
            const int col = n0 + wc + nt * 16 + fm;
#pragma unroll
            for (int i = 0; i < 4; ++i) {
                const int row = wr + mt * 16 + kg * 4 + i;
                float g = ag[mt][nt][i], u = au[mt][nt][i];
                float yv = g / (1.f + expf(-g)) * u;
                Y[(size_t)(slot * 128 + row) * N + col] = (ushort_t)f2bf(yv);
            }
        }
}

// ---- Down v6: ATOMIC-FREE. Shared z-split 4 -> Psh[z][tok][col] plain stores;
// routed z=1 (22 ksteps over IDIM) -> Prt[slot*128+row][col] plain stores.
// Single-buffer 33KB LDS + __syncthreads (4 blocks/CU TLP — proven v3 style).
__global__ __launch_bounds__(256) void down_all(
    const ushort_t* __restrict__ Ysh, const ushort_t* __restrict__ Yr,
    const ushort_t* __restrict__ swtd, const ushort_t* __restrict__ wtd,
    float* __restrict__ Psh, float* __restrict__ Prt,
    const int* __restrict__ slot_e, const int* __restrict__ nslots)
{
    const int id = blockIdx.x;
    int n0, slot, kbase, K;
    const ushort_t* Yb;
    const ushort_t* Wd;
    float* P;
    if (id < 512) {
        n0 = (id & 15) * 128; slot = (id >> 4) & 7;
        const int z = id >> 7;
        K = SIDIM; kbase = z * 1408;
        Yb = Ysh + (size_t)slot * 128 * K;
        Wd = swtd;
        P = Psh + ((size_t)z * T_TOK + (size_t)slot * 128) * HDIM;
    } else {
        const int id2 = id - 512;
        n0 = (id2 & 15) * 128;
        slot = id2 >> 4;
        if (slot >= nslots[0]) return;
        const int e = slot_e[slot];
        K = IDIM; kbase = 0;
        Yb = Yr + (size_t)slot * 128 * K;
        Wd = wtd + (size_t)e * IDIM * HDIM;
        P = Prt + (size_t)slot * 128 * HDIM;
    }
    const int tid = threadIdx.x, lane = tid & 63, wid = tid >> 6;
    const int wr = (wid >> 1) * 64;
    const int wc = (wid & 1) * 64;
    const int fm = lane & 15, kg = lane >> 4;

    __shared__ __align__(16) ushort_t Ya[128 * 64];
    __shared__ __align__(16) ushort_t Bd[128 * 64];

    f32x4 acc[4][4];
#pragma unroll
    for (int a = 0; a < 4; ++a)
#pragma unroll
        for (int b = 0; b < 4; ++b) acc[a][b] = f32x4{0.f, 0.f, 0.f, 0.f};

    const int koff = (((tid & 7) ^ ((tid >> 3) & 7))) * 8;
    const ushort_t* pY[4];
    const ushort_t* pW[4];
#pragma unroll
    for (int j = 0; j < 4; ++j) {
        const int r = (tid >> 3) + j * 32;
        pY[j] = Yb + (size_t)r * K + kbase + koff;
        pW[j] = Wd + (size_t)(n0 + r) * K + kbase + koff;
    }

    for (int s = 0; s < 22; ++s) {
        const int k0 = s * 64;
#pragma unroll
        for (int j = 0; j < 4; ++j) {
            async16(pY[j] + k0, &Ya[(j * 256 + wid * 64) * 8]);
            async16(pW[j] + k0, &Bd[(j * 256 + wid * 64) * 8]);
        }
        __syncthreads();

#pragma unroll
        for (int ks = 0; ks < 2; ++ks) {
            const int kx = ((ks * 4 + kg) ^ (fm & 7)) * 8;
            bf16x8 af[4];
#pragma unroll
            for (int mt = 0; mt < 4; ++mt)
                af[mt] = *(const bf16x8*)&Ya[(wr + mt * 16 + fm) * 64 + kx];
#pragma unroll
            for (int nt = 0; nt < 4; ++nt) {
                bf16x8 bfv = *(const bf16x8*)&Bd[(wc + nt * 16 + fm) * 64 + kx];
#pragma unroll
                for (int mt = 0; mt < 4; ++mt)
                    acc[mt][nt] = __builtin_amdgcn_mfma_f32_16x16x32_bf16(af[mt], bfv, acc[mt][nt], 0, 0, 0);
            }
        }
        __syncthreads();
    }

#pragma unroll
    for (int mt = 0; mt < 4; ++mt)
#pragma unroll
        for (int nt = 0; nt < 4; ++nt) {
            const int col = n0 + wc + nt * 16 + fm;
#pragma unroll
            for (int i = 0; i < 4; ++i) {
                const int row = wr + mt * 16 + kg * 4 + i;
                P[(size_t)row * HDIM + col] = acc[mt][nt][i];
            }
        }
}

// ---- Combine: out = sgate*(sum_z Psh) + w0*Prt[r0] + w1*Prt[r1]. 8 cols/thread.
__global__ __launch_bounds__(256) void combine_kernel(
    const float* __restrict__ Psh, const float* __restrict__ Prt,
    const float* __restrict__ sgate, const float* __restrict__ aw,
    const int* __restrict__ apos, const int* __restrict__ sbase,
    float* __restrict__ out)
{
    const int t = blockIdx.x;
    const int c = threadIdx.x * 8;
    const float sg = sgate[t];
    const float w0 = aw[t * 2], w1 = aw[t * 2 + 1];
    const int a0 = apos[t * 2], a1 = apos[t * 2 + 1];
    const size_t r0 = (size_t)(sbase[a0 >> 10] * 128 + (a0 & 1023)) * HDIM + c;
    const size_t r1 = (size_t)(sbase[a1 >> 10] * 128 + (a1 & 1023)) * HDIM + c;
    const size_t tc = (size_t)t * HDIM + c;
    const size_t plane = (size_t)T_TOK * HDIM;

    f32x4 s0 = *(const f32x4*)(Psh + tc);
    f32x4 s1 = *(const f32x4*)(Psh + tc + 4);
#pragma unroll
    for (int z = 1; z < 4; ++z) {
        s0 += *(const f32x4*)(Psh + z * plane + tc);
        s1 += *(const f32x4*)(Psh + z * plane + tc + 4);
    }
    f32x4 q0 = *(const f32x4*)(Prt + r0);
    f32x4 q1 = *(const f32x4*)(Prt + r0 + 4);
    f32x4 u0 = *(const f32x4*)(Prt + r1);
    f32x4 u1 = *(const f32x4*)(Prt + r1 + 4);
    f32x4 o0 = sg * s0 + w0 * q0 + w1 * u0;
    f32x4 o1 = sg * s1 + w0 * q1 + w1 * u1;
    *(f32x4*)(out + tc) = o0;
    *(f32x4*)(out + tc + 4) = o1;
}

extern "C" void kernel_launch(void* const* d_in, const int* in_sizes, int n_in,
                              void* d_out, int out_size, void* d_ws, size_t ws_size,
                              hipStream_t stream)
{
    const float* hs  = (const float*)d_in[0];
    const float* gw  = (const float*)d_in[1];
    const float* wg  = (const float*)d_in[2];
    const float* wu  = (const float*)d_in[3];
    const float* wd  = (const float*)d_in[4];
    const float* swg = (const float*)d_in[5];
    const float* swu = (const float*)d_in[6];
    const float* swd = (const float*)d_in[7];
    const float* sgw = (const float*)d_in[8];
    float* out = (float*)d_out;
    char* ws = (char*)d_ws;

    float* sgate        = (float*)(ws + 0x08000);
    int* counts         = (int*)(ws + 0x09000);
    int* nslots         = (int*)(ws + 0x09100);
    int* slot_e         = (int*)(ws + 0x09200);
    int* slot_rb        = (int*)(ws + 0x09300);
    int* sbase          = (int*)(ws + 0x09380);
    int* tok_list       = (int*)(ws + 0x09400);
    ushort_t* zerobuf   = (ushort_t*)(ws + 0x11400);   // 16 KB zeros
    float* aw           = (float*)(ws + 0x15400);      // 8 KB
    int* apos           = (int*)(ws + 0x17400);        // 8 KB
    ushort_t* Xb        = (ushort_t*)(ws + 0x20000);
    ushort_t* Yr        = (ushort_t*)(ws + 0x420000);
    ushort_t* Ysh       = (ushort_t*)(ws + 0xC60000);
    ushort_t* wtg       = (ushort_t*)(ws + 0x1760000);
    ushort_t* wtu       = (ushort_t*)(ws + 0x4360000);
    ushort_t* wtd       = (ushort_t*)(ws + 0x6F60000);
    ushort_t* swtg      = (ushort_t*)(ws + 0x9B60000);
    ushort_t* swtu      = (ushort_t*)(ws + 0xB160000);
    ushort_t* swtd      = (ushort_t*)(ws + 0xC760000);
    // Psh/Prt alias wtg/wtu: those weights are dead once gateup_all completes,
    // and conv_all rewrites them at the start of every launch (stream-ordered).
    float* Psh          = (float*)(ws + 0x1760000);    // 4*1024*2048*4 = 32 MB
    float* Prt          = (float*)(ws + 0x3760000);    // 24*128*2048*4 = 24 MB
    float* out_logits = out + (size_t)T_TOK * HDIM;

    hipMemsetAsync(counts, 0, 256, stream);
    hipMemsetAsync(zerobuf, 0, 16384, stream);

    conv_x<<<dim3(1024), dim3(256), 0, stream>>>(hs, Xb);
    conv_all<<<dim3(25344), dim3(256), 0, stream>>>(
        wg, wu, wd, swg, swu, swd, wtg, wtu, wtd, swtg, swtu, swtd);

    router_kernel<<<dim3(T_TOK), dim3(256), 0, stream>>>(
        hs, gw, sgw, out_logits, aw, apos, sgate, counts, tok_list);
    slot_kernel<<<dim3(1), dim3(64), 0, stream>>>(counts, slot_e, slot_rb, nslots, sbase);

    gateup_all<<<dim3(704 + 22 * MAXSLOTS), dim3(256), 0, stream>>>(
        Xb, swtg, swtu, wtg, wtu, Ysh, Yr,
        slot_e, slot_rb, counts, nslots, tok_list, zerobuf);

    down_all<<<dim3(512 + 16 * MAXSLOTS), dim3(256), 0, stream>>>(
        Ysh, Yr, swtd, wtd, Psh, Prt, slot_e, nslots);

    combine_kernel<<<dim3(T_TOK), dim3(256), 0, stream>>>(
        Psh, Prt, sgate, aw, apos, sbase, out);
}